// Round 3
// baseline (1127.630 us; speedup 1.0000x reference)
//
#include <hip/hip_runtime.h>
#include <hip/hip_cooperative_groups.h>
#include <stdint.h>

namespace cg = cooperative_groups;

// B,I,Din,N,D = 32,1024,32,64,32 ; num_routing = 3
#define II 1024
#define BBc 32
#define NN 64
#define DD 32
#define NDT 2048   // N*D

typedef _Float16 half8 __attribute__((ext_vector_type(8)));
typedef float f32x4 __attribute__((ext_vector_type(4)));

__device__ __forceinline__ half8 ld_cvt8(const float* __restrict__ p) {
  const float4 v0 = *(const float4*)p;
  const float4 v1 = *(const float4*)(p + 4);
  half8 h;
  h[0] = (_Float16)v0.x; h[1] = (_Float16)v0.y; h[2] = (_Float16)v0.z; h[3] = (_Float16)v0.w;
  h[4] = (_Float16)v1.x; h[5] = (_Float16)v1.y; h[6] = (_Float16)v1.z; h[7] = (_Float16)v1.w;
  return h;
}

__device__ __forceinline__ half8 ld_cvt8_nt(const float* __restrict__ p) {
  const f32x4 v0 = __builtin_nontemporal_load((const f32x4*)p);
  const f32x4 v1 = __builtin_nontemporal_load((const f32x4*)(p + 4));
  half8 h;
  h[0] = (_Float16)v0[0]; h[1] = (_Float16)v0[1]; h[2] = (_Float16)v0[2]; h[3] = (_Float16)v0[3];
  h[4] = (_Float16)v1[0]; h[5] = (_Float16)v1[1]; h[6] = (_Float16)v1[2]; h[7] = (_Float16)v1[3];
  return h;
}

// ---------------------------------------------------------------------------
// Phase 1: ih[b][i][nd] (f16) = sum_k x[b,i,k]*W[n,i,d,k] via MFMA 16x16x32.
// bid = i (1024); block handles BOTH nd-halves (afrag reused). Wave-private
// lbuf -> lgkmcnt(0)-only ordering (verified passing in prior rounds).
// ---------------------------------------------------------------------------
__device__ __forceinline__ void phase_einsum(
    const float* __restrict__ x, const float* __restrict__ W,
    _Float16* __restrict__ ih, _Float16 (*lbuf)[32][64], int bid, int t)
{
  const int i = bid;
  const int w = t >> 6, L = t & 63, lm = L & 15, q = L >> 4;
  half8 afrag[2];
#pragma unroll
  for (int mt = 0; mt < 2; ++mt)
    afrag[mt] = ld_cvt8(x + ((size_t)(mt * 16 + lm) * II + i) * 32 + q * 8);

  for (int hf = 0; hf < 2; ++hf) {
    const int ndw = hf * 1024 + w * 256;
    for (int g = 0; g < 4; ++g) {          // 4 groups of 64 nd (4 n-tiles)
#pragma unroll
      for (int nt = 0; nt < 4; ++nt) {
        const int nd = ndw + g * 64 + nt * 16 + lm;
        const int n = nd >> 5, d = nd & 31;
        const half8 bfrag = ld_cvt8_nt(W + (size_t)n * (II * 1024) + (size_t)i * 1024 + d * 32 + q * 8);
        const f32x4 z = {0.f, 0.f, 0.f, 0.f};
        f32x4 acc0 = __builtin_amdgcn_mfma_f32_16x16x32_f16(afrag[0], bfrag, z, 0, 0, 0);
        f32x4 acc1 = __builtin_amdgcn_mfma_f32_16x16x32_f16(afrag[1], bfrag, z, 0, 0, 0);
        // C/D layout: col=lane&15 (nd), row=quad*4+reg (b)
#pragma unroll
        for (int r = 0; r < 4; ++r) {
          lbuf[w][q * 4 + r][nt * 16 + lm]      = (_Float16)acc0[r];
          lbuf[w][16 + q * 4 + r][nt * 16 + lm] = (_Float16)acc1[r];
        }
      }
      asm volatile("s_waitcnt lgkmcnt(0)" ::: "memory");
      __builtin_amdgcn_sched_barrier(0);
#pragma unroll
      for (int j = 0; j < 4; ++j) {
        const int row = j * 8 + (L >> 3);
        const int ndo = (L & 7) * 8;
        const half8 v = *(const half8*)&lbuf[w][row][ndo];
        *(half8*)(ih + ((size_t)row * II + i) * NDT + ndw + g * 64 + ndo) = v;
      }
      __builtin_amdgcn_sched_barrier(0);   // keep next g's LDS writes after reads
    }
  }
}

// ---------------------------------------------------------------------------
// Phase 2: partial sums over i of ih -> s0p[is][b][nd]. bid: b=bid>>5, is=bid&31.
// ---------------------------------------------------------------------------
__device__ __forceinline__ void phase_s0red(
    const _Float16* __restrict__ ih, float* __restrict__ s0p, int bid, int t)
{
  const int b = bid >> 5, is = bid & 31;
  const _Float16* base = ih + ((size_t)b * II + is * 32) * NDT + t * 8;
  float a[8] = {};
#pragma unroll 8
  for (int ii = 0; ii < 32; ++ii) {
    const half8 v = *(const half8*)(base + (size_t)ii * NDT);
#pragma unroll
    for (int j = 0; j < 8; ++j) a[j] += (float)v[j];
  }
  float* o = s0p + ((size_t)is * BBc + b) * NDT + t * 8;
  *(float4*)(o + 0) = make_float4(a[0], a[1], a[2], a[3]);
  *(float4*)(o + 4) = make_float4(a[4], a[5], a[6], a[7]);
}

// ---------------------------------------------------------------------------
// Phase 4/6: one routing iteration. bid: b=bid&31, it=bid>>5 (32 its, 32 i each).
// lane = n; wave handles 8 i rows. Keeps ih rows as raw half8 (reg pressure).
// ---------------------------------------------------------------------------
__device__ __forceinline__ void phase_route(
    const _Float16* __restrict__ ih, const float* __restrict__ o1,
    const float* __restrict__ o2, float* __restrict__ rpart,
    float (*red)[NN][DD + 1], int bid, int t)
{
  const int b = bid & 31, it = bid >> 5;
  const int w = t >> 6, lane = t & 63;   // lane = n
  float outr[DD];
  {
    const float4* p1 = (const float4*)(o1 + ((size_t)b * NN + lane) * DD);
    if (o2 != nullptr) {
      const float4* p2 = (const float4*)(o2 + ((size_t)b * NN + lane) * DD);
#pragma unroll
      for (int qq = 0; qq < 8; ++qq) {
        const float4 v1 = p1[qq], v2 = p2[qq];
        outr[qq * 4 + 0] = v1.x + v2.x; outr[qq * 4 + 1] = v1.y + v2.y;
        outr[qq * 4 + 2] = v1.z + v2.z; outr[qq * 4 + 3] = v1.w + v2.w;
      }
    } else {
#pragma unroll
      for (int qq = 0; qq < 8; ++qq) {
        const float4 v1 = p1[qq];
        outr[qq * 4 + 0] = v1.x; outr[qq * 4 + 1] = v1.y;
        outr[qq * 4 + 2] = v1.z; outr[qq * 4 + 3] = v1.w;
      }
    }
  }
  float racc[DD] = {};
  const _Float16* ibase = ih + (size_t)b * II * NDT + lane * DD;
  for (int jj = 0; jj < 8; ++jj) {
    const int i = it * 32 + w * 8 + jj;
    const half8* r8 = (const half8*)(ibase + (size_t)i * NDT);
    const half8 v0 = r8[0], v1 = r8[1], v2 = r8[2], v3 = r8[3];
    float dist = 0.f;
#pragma unroll
    for (int j = 0; j < 8; ++j) dist += outr[j]      * (float)v0[j];
#pragma unroll
    for (int j = 0; j < 8; ++j) dist += outr[8 + j]  * (float)v1[j];
#pragma unroll
    for (int j = 0; j < 8; ++j) dist += outr[16 + j] * (float)v2[j];
#pragma unroll
    for (int j = 0; j < 8; ++j) dist += outr[24 + j] * (float)v3[j];
    // softmax over n = 64-lane wave reduce
    float m = dist;
#pragma unroll
    for (int off = 32; off > 0; off >>= 1) m = fmaxf(m, __shfl_xor(m, off));
    const float e = __expf(dist - m);
    float ss = e;
#pragma unroll
    for (int off = 32; off > 0; off >>= 1) ss += __shfl_xor(ss, off);
    const float route = e / ss;
#pragma unroll
    for (int j = 0; j < 8; ++j) racc[j]      += route * (float)v0[j];
#pragma unroll
    for (int j = 0; j < 8; ++j) racc[8 + j]  += route * (float)v1[j];
#pragma unroll
    for (int j = 0; j < 8; ++j) racc[16 + j] += route * (float)v2[j];
#pragma unroll
    for (int j = 0; j < 8; ++j) racc[24 + j] += route * (float)v3[j];
  }
  __syncthreads();   // red buffer may be in use by a previous phase's tail
#pragma unroll
  for (int d = 0; d < DD; ++d) red[w][lane][d] = racc[d];
  __syncthreads();
  for (int j = t; j < NN * DD; j += 256) {
    const int n = j >> 5, d = j & 31;
    const float v = red[0][n][d] + red[1][n][d] + red[2][n][d] + red[3][n][d];
    rpart[((size_t)it * BBc + b) * NDT + n * DD + d] = v;
  }
}

// ---------------------------------------------------------------------------
// Phase 3/5/7: reduce 32 partials -> scale -> squash. Only bid<256 active.
// ---------------------------------------------------------------------------
__device__ __forceinline__ void phase_rs(
    const float* __restrict__ parts, const int nparts, const float scale,
    float* __restrict__ dst, int bid, int t)
{
  if (bid >= 256) return;
  const int b = bid >> 3, ng = bid & 7;
  const int n = ng * 8 + (t >> 5), d = t & 31;
  const size_t off = (size_t)b * NDT + n * DD + d;
  float s = 0.f;
  for (int c = 0; c < nparts; ++c) s += parts[(size_t)c * (BBc * NDT) + off];
  s *= scale;
  float sq = s * s;
#pragma unroll
  for (int m = 16; m > 0; m >>= 1) sq += __shfl_xor(sq, m);
  const float f = sq / ((1.f + sq) * sqrtf(sq + 1e-7f));
  dst[off] = s * f;
}

// ---------------------------------------------------------------------------
// Fused cooperative kernel: 1024 blocks x 256 thr, 4 blocks/CU co-resident.
// LDS = max(16KB einsum, 33.8KB route) = 33.8KB -> 135KB/CU. VGPR capped 128.
// ---------------------------------------------------------------------------
__global__ __launch_bounds__(256, 4) void fused_caps(
    const float* __restrict__ x, const float* __restrict__ W,
    _Float16* __restrict__ ih, float* __restrict__ s0p, float* __restrict__ rpart,
    float* __restrict__ outA, float* __restrict__ outB, float* __restrict__ outF)
{
  __shared__ union SH {
    _Float16 lbuf[4][32][64];       // 16 KB  (phase 1)
    float    red[4][NN][DD + 1];    // 33.8 KB (phases 4/6)
  } sh;
  cg::grid_group gg = cg::this_grid();
  const int bid = blockIdx.x, t = threadIdx.x;

  phase_einsum(x, W, ih, sh.lbuf, bid, t);
  gg.sync();
  phase_s0red(ih, s0p, bid, t);
  gg.sync();
  phase_rs(s0p, 32, 1.f / 64.f, outA, bid, t);       // outputs_0
  gg.sync();
  phase_route(ih, outA, nullptr, rpart, sh.red, bid, t);
  gg.sync();
  phase_rs(rpart, 32, 1.f, outB, bid, t);            // outputs_1
  gg.sync();
  phase_route(ih, outA, outB, rpart, sh.red, bid, t); // l2 = <o0+o1, ih>
  gg.sync();
  phase_rs(rpart, 32, 1.f, outF, bid, t);            // outputs_2
}

// ---------------------------------------------------------------------------
// Fallback separate kernels (thin wrappers over the same phases) in case the
// cooperative launch is refused (e.g. not capturable). Correctness-identical.
// ---------------------------------------------------------------------------
__global__ __launch_bounds__(256) void k1_sep(
    const float* __restrict__ x, const float* __restrict__ W, _Float16* __restrict__ ih) {
  __shared__ _Float16 lbuf[4][32][64];
  phase_einsum(x, W, ih, lbuf, blockIdx.x, threadIdx.x);
}
__global__ __launch_bounds__(256) void s0_sep(
    const _Float16* __restrict__ ih, float* __restrict__ s0p) {
  phase_s0red(ih, s0p, blockIdx.x, threadIdx.x);
}
__global__ __launch_bounds__(256) void route_sep(
    const _Float16* __restrict__ ih, const float* __restrict__ o1,
    const float* __restrict__ o2, float* __restrict__ rpart) {
  __shared__ float red[4][NN][DD + 1];
  phase_route(ih, o1, o2, rpart, red, blockIdx.x, threadIdx.x);
}
__global__ __launch_bounds__(256) void rs_sep(
    const float* __restrict__ parts, const int nparts, const float scale,
    float* __restrict__ dst) {
  phase_rs(parts, nparts, scale, dst, blockIdx.x, threadIdx.x);
}

extern "C" void kernel_launch(void* const* d_in, const int* in_sizes, int n_in,
                              void* d_out, int out_size, void* d_ws, size_t ws_size,
                              hipStream_t stream) {
  (void)in_sizes; (void)n_in; (void)out_size; (void)ws_size;
  const float* x = (const float*)d_in[0];
  const float* W = (const float*)d_in[1];
  // num_routing fixed at 3 by setup_inputs; schedule hard-coded.

  char* ws = (char*)d_ws;
  _Float16* ih = (_Float16*)ws;                             // 128 MB
  size_t off = (size_t)BBc * II * NDT * 2;
  float* s0p = (float*)(ws + off); off += (size_t)32 * BBc * NDT * 4;   // 8 MB
  float* rpart = (float*)(ws + off); off += (size_t)32 * BBc * NDT * 4; // 8 MB
  float* outA = (float*)(ws + off); off += (size_t)BBc * NDT * 4;       // 256 KB
  float* outB = (float*)(ws + off);                                     // 256 KB
  float* outF = (float*)d_out;

  void* kargs[] = {(void*)&x, (void*)&W, (void*)&ih, (void*)&s0p,
                   (void*)&rpart, (void*)&outA, (void*)&outB, (void*)&outF};
  hipError_t rc = hipLaunchCooperativeKernel((const void*)fused_caps,
                                             dim3(1024), dim3(256), kargs, 0, stream);
  if (rc != hipSuccess) {
    // fall back to the proven multi-kernel pipeline
    k1_sep<<<dim3(1024), 256, 0, stream>>>(x, W, ih);
    s0_sep<<<dim3(1024), 256, 0, stream>>>(ih, s0p);
    rs_sep<<<dim3(256), 256, 0, stream>>>(s0p, 32, 1.f / 64.f, outA);
    route_sep<<<dim3(1024), 256, 0, stream>>>(ih, outA, nullptr, rpart);
    rs_sep<<<dim3(256), 256, 0, stream>>>(rpart, 32, 1.f, outB);
    route_sep<<<dim3(1024), 256, 0, stream>>>(ih, outA, outB, rpart);
    rs_sep<<<dim3(256), 256, 0, stream>>>(rpart, 32, 1.f, outF);
  }
}

// Round 4
// 807.533 us; speedup vs baseline: 1.3964x; 1.3964x over previous
//
#include <hip/hip_runtime.h>
#include <hip/hip_cooperative_groups.h>
#include <stdint.h>

namespace cg = cooperative_groups;

// B,I,Din,N,D = 32,1024,32,64,32 ; num_routing = 3
#define II 1024
#define BBc 32
#define NN 64
#define DD 32
#define NDT 2048   // N*D
#define LBP 72     // padded lbuf row (halfs): 144B rows, 16B-aligned, breaks
                   // the 8-way bank conflict of 128B rows (q*4 rows -> +16 banks)

typedef _Float16 half8 __attribute__((ext_vector_type(8)));
typedef float f32x4 __attribute__((ext_vector_type(4)));

__device__ __forceinline__ half8 ld_cvt8(const float* __restrict__ p) {
  const float4 v0 = *(const float4*)p;
  const float4 v1 = *(const float4*)(p + 4);
  half8 h;
  h[0] = (_Float16)v0.x; h[1] = (_Float16)v0.y; h[2] = (_Float16)v0.z; h[3] = (_Float16)v0.w;
  h[4] = (_Float16)v1.x; h[5] = (_Float16)v1.y; h[6] = (_Float16)v1.z; h[7] = (_Float16)v1.w;
  return h;
}

__device__ __forceinline__ half8 ld_cvt8_nt(const float* __restrict__ p) {
  const f32x4 v0 = __builtin_nontemporal_load((const f32x4*)p);
  const f32x4 v1 = __builtin_nontemporal_load((const f32x4*)(p + 4));
  half8 h;
  h[0] = (_Float16)v0[0]; h[1] = (_Float16)v0[1]; h[2] = (_Float16)v0[2]; h[3] = (_Float16)v0[3];
  h[4] = (_Float16)v1[0]; h[5] = (_Float16)v1[1]; h[6] = (_Float16)v1[2]; h[7] = (_Float16)v1[3];
  return h;
}

// ---------------------------------------------------------------------------
// Phase 1: ih[b][i][nd] (f16) = sum_k x[b,i,k]*W[n,i,d,k] via MFMA 16x16x32.
// 512 blocks: each handles i = bid*2+{0,1}, both nd-halves. Wave-private lbuf,
// lgkmcnt(0)-only ordering (no barrier -> W-load queue never drains).
// ---------------------------------------------------------------------------
__device__ __forceinline__ void phase_einsum(
    const float* __restrict__ x, const float* __restrict__ W,
    _Float16* __restrict__ ih, _Float16 (*lbuf)[32][LBP], int bid, int t)
{
  const int w = t >> 6, L = t & 63, lm = L & 15, q = L >> 4;
  for (int sub = 0; sub < 2; ++sub) {
    const int i = bid * 2 + sub;
    half8 afrag[2];
#pragma unroll
    for (int mt = 0; mt < 2; ++mt)
      afrag[mt] = ld_cvt8(x + ((size_t)(mt * 16 + lm) * II + i) * 32 + q * 8);

    for (int hf = 0; hf < 2; ++hf) {
      const int ndw = hf * 1024 + w * 256;
      for (int g = 0; g < 4; ++g) {          // 4 groups of 64 nd (4 n-tiles)
#pragma unroll
        for (int nt = 0; nt < 4; ++nt) {
          const int nd = ndw + g * 64 + nt * 16 + lm;
          const int n = nd >> 5, d = nd & 31;
          const half8 bfrag = ld_cvt8_nt(W + (size_t)n * (II * 1024) + (size_t)i * 1024 + d * 32 + q * 8);
          const f32x4 z = {0.f, 0.f, 0.f, 0.f};
          f32x4 acc0 = __builtin_amdgcn_mfma_f32_16x16x32_f16(afrag[0], bfrag, z, 0, 0, 0);
          f32x4 acc1 = __builtin_amdgcn_mfma_f32_16x16x32_f16(afrag[1], bfrag, z, 0, 0, 0);
          // C/D layout: col=lane&15 (nd), row=quad*4+reg (b)
#pragma unroll
          for (int r = 0; r < 4; ++r) {
            lbuf[w][q * 4 + r][nt * 16 + lm]      = (_Float16)acc0[r];
            lbuf[w][16 + q * 4 + r][nt * 16 + lm] = (_Float16)acc1[r];
          }
        }
        asm volatile("s_waitcnt lgkmcnt(0)" ::: "memory");
        __builtin_amdgcn_sched_barrier(0);
        // read back 32 b-rows x 64 nd; store: 8 lanes x 16B = one 128B row
#pragma unroll
        for (int j = 0; j < 4; ++j) {
          const int row = j * 8 + (L >> 3);
          const int ndo = (L & 7) * 8;
          const half8 v = *(const half8*)&lbuf[w][row][ndo];
          *(half8*)(ih + ((size_t)row * II + i) * NDT + ndw + g * 64 + ndo) = v;
        }
        __builtin_amdgcn_sched_barrier(0);   // keep next g's LDS writes after reads
      }
    }
  }
}

// ---------------------------------------------------------------------------
// Phase 2: partial sums over i of ih -> s0p[is][b][nd]. 512 blocks:
// b=bid>>4, is=bid&15, 64 i-rows each.
// ---------------------------------------------------------------------------
__device__ __forceinline__ void phase_s0red(
    const _Float16* __restrict__ ih, float* __restrict__ s0p, int bid, int t)
{
  const int b = bid >> 4, is = bid & 15;
  const _Float16* base = ih + ((size_t)b * II + is * 64) * NDT + t * 8;
  float a[8] = {};
#pragma unroll 8
  for (int ii = 0; ii < 64; ++ii) {
    const half8 v = *(const half8*)(base + (size_t)ii * NDT);
#pragma unroll
    for (int j = 0; j < 8; ++j) a[j] += (float)v[j];
  }
  float* o = s0p + ((size_t)is * BBc + b) * NDT + t * 8;
  *(float4*)(o + 0) = make_float4(a[0], a[1], a[2], a[3]);
  *(float4*)(o + 4) = make_float4(a[4], a[5], a[6], a[7]);
}

// ---------------------------------------------------------------------------
// Phase 4/6: one routing iteration. 512 blocks: b=bid&31, it=bid>>5 (16 its,
// 64 i each; wave handles 16 i rows). lane = n.
// ---------------------------------------------------------------------------
__device__ __forceinline__ void phase_route(
    const _Float16* __restrict__ ih, const float* __restrict__ o1,
    const float* __restrict__ o2, float* __restrict__ rpart,
    float (*red)[NN][DD + 1], int bid, int t)
{
  const int b = bid & 31, it = bid >> 5;
  const int w = t >> 6, lane = t & 63;   // lane = n
  float outr[DD];
  {
    const float4* p1 = (const float4*)(o1 + ((size_t)b * NN + lane) * DD);
    if (o2 != nullptr) {
      const float4* p2 = (const float4*)(o2 + ((size_t)b * NN + lane) * DD);
#pragma unroll
      for (int qq = 0; qq < 8; ++qq) {
        const float4 v1 = p1[qq], v2 = p2[qq];
        outr[qq * 4 + 0] = v1.x + v2.x; outr[qq * 4 + 1] = v1.y + v2.y;
        outr[qq * 4 + 2] = v1.z + v2.z; outr[qq * 4 + 3] = v1.w + v2.w;
      }
    } else {
#pragma unroll
      for (int qq = 0; qq < 8; ++qq) {
        const float4 v1 = p1[qq];
        outr[qq * 4 + 0] = v1.x; outr[qq * 4 + 1] = v1.y;
        outr[qq * 4 + 2] = v1.z; outr[qq * 4 + 3] = v1.w;
      }
    }
  }
  float racc[DD] = {};
  const _Float16* ibase = ih + (size_t)b * II * NDT + lane * DD;
#pragma unroll 2
  for (int jj = 0; jj < 16; ++jj) {
    const int i = it * 64 + w * 16 + jj;
    const half8* r8 = (const half8*)(ibase + (size_t)i * NDT);
    const half8 v0 = r8[0], v1 = r8[1], v2 = r8[2], v3 = r8[3];
    float dist = 0.f;
#pragma unroll
    for (int j = 0; j < 8; ++j) dist += outr[j]      * (float)v0[j];
#pragma unroll
    for (int j = 0; j < 8; ++j) dist += outr[8 + j]  * (float)v1[j];
#pragma unroll
    for (int j = 0; j < 8; ++j) dist += outr[16 + j] * (float)v2[j];
#pragma unroll
    for (int j = 0; j < 8; ++j) dist += outr[24 + j] * (float)v3[j];
    // softmax over n = 64-lane wave reduce
    float m = dist;
#pragma unroll
    for (int off = 32; off > 0; off >>= 1) m = fmaxf(m, __shfl_xor(m, off));
    const float e = __expf(dist - m);
    float ss = e;
#pragma unroll
    for (int off = 32; off > 0; off >>= 1) ss += __shfl_xor(ss, off);
    const float route = e / ss;
#pragma unroll
    for (int j = 0; j < 8; ++j) racc[j]      += route * (float)v0[j];
#pragma unroll
    for (int j = 0; j < 8; ++j) racc[8 + j]  += route * (float)v1[j];
#pragma unroll
    for (int j = 0; j < 8; ++j) racc[16 + j] += route * (float)v2[j];
#pragma unroll
    for (int j = 0; j < 8; ++j) racc[24 + j] += route * (float)v3[j];
  }
  __syncthreads();   // red buffer may be in use by a previous phase
#pragma unroll
  for (int d = 0; d < DD; ++d) red[w][lane][d] = racc[d];
  __syncthreads();
  for (int j = t; j < NN * DD; j += 256) {
    const int n = j >> 5, d = j & 31;
    const float v = red[0][n][d] + red[1][n][d] + red[2][n][d] + red[3][n][d];
    rpart[((size_t)it * BBc + b) * NDT + n * DD + d] = v;
  }
}

// ---------------------------------------------------------------------------
// Phase 3/5/7: reduce nparts partials -> scale -> squash. Only bid<256 active.
// ---------------------------------------------------------------------------
__device__ __forceinline__ void phase_rs(
    const float* __restrict__ parts, const int nparts, const float scale,
    float* __restrict__ dst, int bid, int t)
{
  if (bid >= 256) return;
  const int b = bid >> 3, ng = bid & 7;
  const int n = ng * 8 + (t >> 5), d = t & 31;
  const size_t off = (size_t)b * NDT + n * DD + d;
  float s = 0.f;
  for (int c = 0; c < nparts; ++c) s += parts[(size_t)c * (BBc * NDT) + off];
  s *= scale;
  float sq = s * s;
#pragma unroll
  for (int m = 16; m > 0; m >>= 1) sq += __shfl_xor(sq, m);
  const float f = sq / ((1.f + sq) * sqrtf(sq + 1e-7f));
  dst[off] = s * f;
}

// ---------------------------------------------------------------------------
// Fused cooperative kernel: 512 blocks x 256 thr, 2 blocks/CU co-resident.
// waves_per_eu(2,2): VGPR budget 256/wave — round-3's VGPR=64 allocation
// collapsed ILP (VALUBusy 2.5%, everything latency-stalled); give the
// compiler the full register file so loads stay in flight.
// ---------------------------------------------------------------------------
__global__ __launch_bounds__(256)
__attribute__((amdgpu_waves_per_eu(2, 2)))
void fused_caps(
    const float* __restrict__ x, const float* __restrict__ W,
    _Float16* __restrict__ ih, float* __restrict__ s0p, float* __restrict__ rpart,
    float* __restrict__ outA, float* __restrict__ outB, float* __restrict__ outF)
{
  __shared__ union SH {
    _Float16 lbuf[4][32][LBP];      // 18 KB  (phase 1)
    float    red[4][NN][DD + 1];    // 33.8 KB (phases 4/6)
  } sh;
  cg::grid_group gg = cg::this_grid();
  const int bid = blockIdx.x, t = threadIdx.x;

  phase_einsum(x, W, ih, sh.lbuf, bid, t);
  gg.sync();
  phase_s0red(ih, s0p, bid, t);
  gg.sync();
  phase_rs(s0p, 16, 1.f / 64.f, outA, bid, t);       // outputs_0
  gg.sync();
  phase_route(ih, outA, nullptr, rpart, sh.red, bid, t);
  gg.sync();
  phase_rs(rpart, 16, 1.f, outB, bid, t);            // outputs_1
  gg.sync();
  phase_route(ih, outA, outB, rpart, sh.red, bid, t); // l2 = <o0+o1, ih>
  gg.sync();
  phase_rs(rpart, 16, 1.f, outF, bid, t);            // outputs_2
}

// ---------------------------------------------------------------------------
// Fallback separate kernels in case cooperative launch is refused.
// ---------------------------------------------------------------------------
__global__ __launch_bounds__(256) void k1_sep(
    const float* __restrict__ x, const float* __restrict__ W, _Float16* __restrict__ ih) {
  __shared__ _Float16 lbuf[4][32][LBP];
  phase_einsum(x, W, ih, lbuf, blockIdx.x, threadIdx.x);
}
__global__ __launch_bounds__(256) void s0_sep(
    const _Float16* __restrict__ ih, float* __restrict__ s0p) {
  phase_s0red(ih, s0p, blockIdx.x, threadIdx.x);
}
__global__ __launch_bounds__(256) void route_sep(
    const _Float16* __restrict__ ih, const float* __restrict__ o1,
    const float* __restrict__ o2, float* __restrict__ rpart) {
  __shared__ float red[4][NN][DD + 1];
  phase_route(ih, o1, o2, rpart, red, blockIdx.x, threadIdx.x);
}
__global__ __launch_bounds__(256) void rs_sep(
    const float* __restrict__ parts, const int nparts, const float scale,
    float* __restrict__ dst) {
  phase_rs(parts, nparts, scale, dst, blockIdx.x, threadIdx.x);
}

extern "C" void kernel_launch(void* const* d_in, const int* in_sizes, int n_in,
                              void* d_out, int out_size, void* d_ws, size_t ws_size,
                              hipStream_t stream) {
  (void)in_sizes; (void)n_in; (void)out_size; (void)ws_size;
  const float* x = (const float*)d_in[0];
  const float* W = (const float*)d_in[1];
  // num_routing fixed at 3 by setup_inputs; schedule hard-coded.

  char* ws = (char*)d_ws;
  _Float16* ih = (_Float16*)ws;                             // 128 MB
  size_t off = (size_t)BBc * II * NDT * 2;
  float* s0p = (float*)(ws + off); off += (size_t)16 * BBc * NDT * 4;   // 4 MB
  float* rpart = (float*)(ws + off); off += (size_t)16 * BBc * NDT * 4; // 4 MB
  float* outA = (float*)(ws + off); off += (size_t)BBc * NDT * 4;       // 256 KB
  float* outB = (float*)(ws + off);                                     // 256 KB
  float* outF = (float*)d_out;

  void* kargs[] = {(void*)&x, (void*)&W, (void*)&ih, (void*)&s0p,
                   (void*)&rpart, (void*)&outA, (void*)&outB, (void*)&outF};
  hipError_t rc = hipLaunchCooperativeKernel((const void*)fused_caps,
                                             dim3(512), dim3(256), kargs, 0, stream);
  if (rc != hipSuccess) {
    // fall back to the proven multi-kernel pipeline
    k1_sep<<<dim3(512), 256, 0, stream>>>(x, W, ih);
    s0_sep<<<dim3(512), 256, 0, stream>>>(ih, s0p);
    rs_sep<<<dim3(256), 256, 0, stream>>>(s0p, 16, 1.f / 64.f, outA);
    route_sep<<<dim3(512), 256, 0, stream>>>(ih, outA, nullptr, rpart);
    rs_sep<<<dim3(256), 256, 0, stream>>>(rpart, 16, 1.f, outB);
    route_sep<<<dim3(512), 256, 0, stream>>>(ih, outA, outB, rpart);
    rs_sep<<<dim3(256), 256, 0, stream>>>(rpart, 16, 1.f, outF);
  }
}

// Round 5
// 494.541 us; speedup vs baseline: 2.2802x; 1.6329x over previous
//
#include <hip/hip_runtime.h>
#include <stdint.h>

// B,I,Din,N,D = 32,1024,32,64,32 ; num_routing = 3
#define II 1024
#define BBc 32
#define NN 64
#define DD 32
#define NDT 2048   // N*D
#define LBP 72     // padded lbuf row (halfs): 144B rows -> lane-quads land on
                   // +16-bank offsets (2-way, free) instead of 4-way at 128B

typedef _Float16 half8 __attribute__((ext_vector_type(8)));
typedef float f32x4 __attribute__((ext_vector_type(4)));

__device__ __forceinline__ half8 ld_cvt8(const float* __restrict__ p) {
  const float4 v0 = *(const float4*)p;
  const float4 v1 = *(const float4*)(p + 4);
  half8 h;
  h[0] = (_Float16)v0.x; h[1] = (_Float16)v0.y; h[2] = (_Float16)v0.z; h[3] = (_Float16)v0.w;
  h[4] = (_Float16)v1.x; h[5] = (_Float16)v1.y; h[6] = (_Float16)v1.z; h[7] = (_Float16)v1.w;
  return h;
}

__device__ __forceinline__ half8 ld_cvt8_nt(const float* __restrict__ p) {
  const f32x4 v0 = __builtin_nontemporal_load((const f32x4*)p);
  const f32x4 v1 = __builtin_nontemporal_load((const f32x4*)(p + 4));
  half8 h;
  h[0] = (_Float16)v0[0]; h[1] = (_Float16)v0[1]; h[2] = (_Float16)v0[2]; h[3] = (_Float16)v0[3];
  h[4] = (_Float16)v1[0]; h[5] = (_Float16)v1[1]; h[6] = (_Float16)v1[2]; h[7] = (_Float16)v1[3];
  return h;
}

// ---------------------------------------------------------------------------
// k1: ih[b][i][n*32+d] (f16) = sum_k x[b,i,k] * W[n,i,d,k] via MFMA 16x16x32.
// grid (1024 i, 2 nd-half), block 256 = 4 waves; wave owns a 256-wide nd span.
// lbuf is WAVE-PRIVATE: DS ops from one wave complete IN ORDER, so no
// barrier and no manual waitcnt is needed — and with no sched_barrier the
// compiler is free to hoist group g+1's W loads above group g's readback
// (software pipelining the W stream). Fences here previously blocked that.
// ---------------------------------------------------------------------------
__global__ __launch_bounds__(256) void k1_mfma(
    const float* __restrict__ x, const float* __restrict__ W,
    _Float16* __restrict__ ih)
{
  __shared__ _Float16 lbuf[4][32][LBP];   // [wave][b][nd-local], 18 KB
  const int t = threadIdx.x;
  const int i = blockIdx.x;
  const int half_ = blockIdx.y;
  const int w = t >> 6;
  const int L = t & 63;
  const int lm = L & 15, q = L >> 4;

  // A fragments for the 2 m-tiles (b 0-15, 16-31): A[m=lane&15][k=quad*8+j]
  half8 afrag[2];
#pragma unroll
  for (int mt = 0; mt < 2; ++mt)
    afrag[mt] = ld_cvt8(x + ((size_t)(mt * 16 + lm) * II + i) * 32 + q * 8);

  const int ndw = half_ * 1024 + w * 256;
  for (int g = 0; g < 4; ++g) {          // 4 groups of 64 nd (4 n-tiles)
#pragma unroll
    for (int nt = 0; nt < 4; ++nt) {
      const int nd = ndw + g * 64 + nt * 16 + lm;
      const int n = nd >> 5, d = nd & 31;
      const half8 bfrag = ld_cvt8_nt(W + (size_t)n * (II * 1024) + (size_t)i * 1024 + d * 32 + q * 8);
      const f32x4 z = {0.f, 0.f, 0.f, 0.f};
      f32x4 acc0 = __builtin_amdgcn_mfma_f32_16x16x32_f16(afrag[0], bfrag, z, 0, 0, 0);
      f32x4 acc1 = __builtin_amdgcn_mfma_f32_16x16x32_f16(afrag[1], bfrag, z, 0, 0, 0);
      // C/D layout: col=lane&15 (nd), row=quad*4+reg (b)
#pragma unroll
      for (int r = 0; r < 4; ++r) {
        lbuf[w][q * 4 + r][nt * 16 + lm]      = (_Float16)acc0[r];
        lbuf[w][16 + q * 4 + r][nt * 16 + lm] = (_Float16)acc1[r];
      }
    }
    // readback: aliasing DS ops keep program order (wave-private, in-order
    // DS pipe); compiler inserts the counted lgkmcnt before the VALU use.
#pragma unroll
    for (int j = 0; j < 4; ++j) {
      const int row = j * 8 + (L >> 3);
      const int ndo = (L & 7) * 8;
      const half8 v = *(const half8*)&lbuf[w][row][ndo];
      *(half8*)(ih + ((size_t)row * II + i) * NDT + ndw + g * 64 + ndo) = v;
    }
  }
}

// ---------------------------------------------------------------------------
// s0red: partial sums over i of ih -> s0p[is][b][nd] (fp32). grid (32 b, 32 is).
// ---------------------------------------------------------------------------
__global__ __launch_bounds__(256) void s0red(
    const _Float16* __restrict__ ih, float* __restrict__ s0p)
{
  const int b = blockIdx.x, is = blockIdx.y;
  const int t = threadIdx.x;
  const _Float16* base = ih + ((size_t)b * II + is * 32) * NDT + t * 8;
  float a[8] = {};
#pragma unroll 8
  for (int ii = 0; ii < 32; ++ii) {
    const half8 v = *(const half8*)(base + (size_t)ii * NDT);
#pragma unroll
    for (int j = 0; j < 8; ++j) a[j] += (float)v[j];
  }
  float* o = s0p + ((size_t)is * BBc + b) * NDT + t * 8;
  *(float4*)(o + 0) = make_float4(a[0], a[1], a[2], a[3]);
  *(float4*)(o + 4) = make_float4(a[4], a[5], a[6], a[7]);
}

// ---------------------------------------------------------------------------
// k3: one routing iteration (logits-free: l_r = <sum of prior outputs, ih>).
// grid (32 b, 64 it) = 2048 blocks (8/CU), block 256 (4 waves). lane = n.
// ---------------------------------------------------------------------------
__global__ __launch_bounds__(256) void k3_route(
    const _Float16* __restrict__ ih, const float* __restrict__ o1,
    const float* __restrict__ o2, float* __restrict__ rpart)
{
  __shared__ float red[4][NN][DD + 1];
  const int t = threadIdx.x;
  const int b = blockIdx.x, it = blockIdx.y;
  const int w = t >> 6, lane = t & 63;   // lane = n
  float outr[DD];
  {
    const float4* p1 = (const float4*)(o1 + ((size_t)b * NN + lane) * DD);
    if (o2 != nullptr) {
      const float4* p2 = (const float4*)(o2 + ((size_t)b * NN + lane) * DD);
#pragma unroll
      for (int qq = 0; qq < 8; ++qq) {
        const float4 v1 = p1[qq], v2 = p2[qq];
        outr[qq * 4 + 0] = v1.x + v2.x; outr[qq * 4 + 1] = v1.y + v2.y;
        outr[qq * 4 + 2] = v1.z + v2.z; outr[qq * 4 + 3] = v1.w + v2.w;
      }
    } else {
#pragma unroll
      for (int qq = 0; qq < 8; ++qq) {
        const float4 v1 = p1[qq];
        outr[qq * 4 + 0] = v1.x; outr[qq * 4 + 1] = v1.y;
        outr[qq * 4 + 2] = v1.z; outr[qq * 4 + 3] = v1.w;
      }
    }
  }
  float racc[DD] = {};
  const _Float16* ibase = ih + (size_t)b * II * NDT + lane * DD;
#pragma unroll
  for (int jj = 0; jj < 4; ++jj) {
    const int i = it * 16 + w * 4 + jj;
    const half8* r8 = (const half8*)(ibase + (size_t)i * NDT);
    const half8 v0 = r8[0], v1 = r8[1], v2 = r8[2], v3 = r8[3];
    float dist = 0.f;
#pragma unroll
    for (int j = 0; j < 8; ++j) dist += outr[j]      * (float)v0[j];
#pragma unroll
    for (int j = 0; j < 8; ++j) dist += outr[8 + j]  * (float)v1[j];
#pragma unroll
    for (int j = 0; j < 8; ++j) dist += outr[16 + j] * (float)v2[j];
#pragma unroll
    for (int j = 0; j < 8; ++j) dist += outr[24 + j] * (float)v3[j];
    // softmax over n = 64-lane wave reduce
    float m = dist;
#pragma unroll
    for (int off = 32; off > 0; off >>= 1) m = fmaxf(m, __shfl_xor(m, off));
    const float e = __expf(dist - m);
    float ss = e;
#pragma unroll
    for (int off = 32; off > 0; off >>= 1) ss += __shfl_xor(ss, off);
    const float route = e / ss;
#pragma unroll
    for (int j = 0; j < 8; ++j) racc[j]      += route * (float)v0[j];
#pragma unroll
    for (int j = 0; j < 8; ++j) racc[8 + j]  += route * (float)v1[j];
#pragma unroll
    for (int j = 0; j < 8; ++j) racc[16 + j] += route * (float)v2[j];
#pragma unroll
    for (int j = 0; j < 8; ++j) racc[24 + j] += route * (float)v3[j];
  }
#pragma unroll
  for (int d = 0; d < DD; ++d) red[w][lane][d] = racc[d];
  __syncthreads();
  for (int j = t; j < NN * DD; j += 256) {
    const int n = j >> 5, d = j & 31;
    const float v = red[0][n][d] + red[1][n][d] + red[2][n][d] + red[3][n][d];
    rpart[((size_t)it * BBc + b) * NDT + n * DD + d] = v;
  }
}

// ---------------------------------------------------------------------------
// k_rs: reduce nparts partials [c][b][nd] -> scale -> squash -> dst[b][n][d].
// ---------------------------------------------------------------------------
__global__ __launch_bounds__(256) void k_rs(
    const float* __restrict__ parts, const int nparts, const float scale,
    float* __restrict__ dst)
{
  const int b = blockIdx.x;
  const int ng = blockIdx.y;
  const int t = threadIdx.x;
  const int n = ng * 8 + (t >> 5), d = t & 31;
  const size_t off = (size_t)b * NDT + n * DD + d;
  float s = 0.f;
  for (int c = 0; c < nparts; ++c) s += parts[(size_t)c * (BBc * NDT) + off];
  s *= scale;
  float sq = s * s;
#pragma unroll
  for (int m = 16; m > 0; m >>= 1) sq += __shfl_xor(sq, m);
  const float f = sq / ((1.f + sq) * sqrtf(sq + 1e-7f));
  dst[off] = s * f;
}

extern "C" void kernel_launch(void* const* d_in, const int* in_sizes, int n_in,
                              void* d_out, int out_size, void* d_ws, size_t ws_size,
                              hipStream_t stream) {
  (void)in_sizes; (void)n_in; (void)out_size; (void)ws_size;
  const float* x = (const float*)d_in[0];
  const float* W = (const float*)d_in[1];
  // num_routing fixed at 3 by setup_inputs; schedule hard-coded.

  char* ws = (char*)d_ws;
  _Float16* ih = (_Float16*)ws;                             // 128 MB
  size_t off = (size_t)BBc * II * NDT * 2;
  float* s0p = (float*)(ws + off); off += (size_t)32 * BBc * NDT * 4;   // 8 MB
  float* rpart = (float*)(ws + off); off += (size_t)64 * BBc * NDT * 4; // 16 MB
  float* outA = (float*)(ws + off); off += (size_t)BBc * NDT * 4;       // 256 KB
  float* outB = (float*)(ws + off);                                     // 256 KB
  float* outF = (float*)d_out;

  k1_mfma<<<dim3(II, 2), 256, 0, stream>>>(x, W, ih);
  s0red<<<dim3(BBc, 32), 256, 0, stream>>>(ih, s0p);
  k_rs<<<dim3(BBc, 8), 256, 0, stream>>>(s0p, 32, 1.f / 64.f, outA);    // outputs_0
  k3_route<<<dim3(BBc, 64), 256, 0, stream>>>(ih, outA, nullptr, rpart);
  k_rs<<<dim3(BBc, 8), 256, 0, stream>>>(rpart, 64, 1.f, outB);         // outputs_1
  k3_route<<<dim3(BBc, 64), 256, 0, stream>>>(ih, outA, outB, rpart);   // l2 = <o0+o1, ih>
  k_rs<<<dim3(BBc, 8), 256, 0, stream>>>(rpart, 64, 1.f, outF);         // outputs_2
}